// Round 1
// 360.498 us; speedup vs baseline: 1.0328x; 1.0328x over previous
//
#include <hip/hip_runtime.h>

// Problem constants
constexpr int kH  = 8;     // heads
constexpr int kD  = 16;    // dim per head
constexpr int kHD = 128;   // H*D
constexpr int kN  = 32;    // neighbors
constexpr int kE  = 32;    // edge feature dim
constexpr int kD0 = 128;   // feats0 channels
constexpr int kD1 = 64;    // feats1 channels
constexpr int kP  = 4;     // positions per block (k1,k2)
constexpr int kP3 = 2;     // positions per block (k3)
constexpr int kPP = 8;     // positions per block (k4)

constexpr float SCALE0   = 0.25f;                 // 1/sqrt(16)
constexpr float SCALE1   = 0.14433756729740643f;  // 1/sqrt(48)
constexpr float SHARED_S = 0.70710678118654752f;  // sqrt(0.5)
constexpr float NEGV     = -1e9f;

// ws layout (floats): sc[n][272] | sv0[n][128] | sv1[n][384]
// After k3_accum, sv0/sv1 are reused in-place as o0/o1 (attn-weighted V sums).

// ---------------------------------------------------------------------------
// K1: self key/value rows + null/self similarity score slots. P positions/block.
// ---------------------------------------------------------------------------
__global__ __launch_bounds__(256) void k1_selfkv(
    const float* __restrict__ q0, const float* __restrict__ q1,
    const float* __restrict__ feats0, const float* __restrict__ feats1,
    const float* __restrict__ Wskv0, const float* __restrict__ Wskv1,
    const float* __restrict__ self_bias, const float* __restrict__ null_bias,
    const float* __restrict__ nk0, const float* __restrict__ nk1,
    const float* __restrict__ hw1,
    float* __restrict__ ws_sc, float* __restrict__ ws_sv0, float* __restrict__ ws_sv1)
{
  const int i0 = blockIdx.x * kP;
  const int t  = threadIdx.x;
  __shared__ __align__(16) float f0s[kP][kD0];
  __shared__ __align__(16) float f1s[kP][kD1 * 3];
  __shared__ __align__(16) float q0s[kP][kHD];
  __shared__ __align__(16) float q1s[kP][kHD * 3];
  __shared__ float sk0L[kP][kHD];
  __shared__ float sk1L[kP][kHD * 3];
  __shared__ float w1s[kH];

  for (int u = t; u < kP * 32; u += 256) { int p = u >> 5, r = u & 31;
    ((float4*)f0s[p])[r] = ((const float4*)(feats0 + (size_t)(i0 + p) * kD0))[r]; }
  for (int u = t; u < kP * 48; u += 256) { int p = u / 48, r = u % 48;
    ((float4*)f1s[p])[r] = ((const float4*)(feats1 + (size_t)(i0 + p) * kD1 * 3))[r]; }
  for (int u = t; u < kP * 32; u += 256) { int p = u >> 5, r = u & 31;
    ((float4*)q0s[p])[r] = ((const float4*)(q0 + (size_t)(i0 + p) * kHD))[r]; }
  for (int u = t; u < kP * 96; u += 256) { int p = u / 96, r = u % 96;
    ((float4*)q1s[p])[r] = ((const float4*)(q1 + (size_t)(i0 + p) * kHD * 3))[r]; }
  if (t < kH) w1s[t] = log1pf(expf(hw1[t]));
  __syncthreads();

  float acc0[kP] = {};
  {
    const float4* wr = (const float4*)(Wskv0 + t * kD0);
    #pragma unroll
    for (int g = 0; g < 32; ++g) {
      float4 w = wr[g]; int c = g * 4;
      #pragma unroll
      for (int p = 0; p < kP; ++p)
        acc0[p] += w.x * f0s[p][c] + w.y * f0s[p][c + 1]
                 + w.z * f0s[p][c + 2] + w.w * f0s[p][c + 3];
    }
  }
  float acc1[kP][3] = {};
  {
    const float4* wr = (const float4*)(Wskv1 + t * kD1);
    #pragma unroll
    for (int g = 0; g < 16; ++g) {
      float4 w = wr[g]; int c = g * 4;
      float wv[4] = {w.x, w.y, w.z, w.w};
      #pragma unroll
      for (int q = 0; q < 4; ++q) {
        #pragma unroll
        for (int p = 0; p < kP; ++p) {
          const float* fp = &f1s[p][(c + q) * 3];
          acc1[p][0] += wv[q] * fp[0];
          acc1[p][1] += wv[q] * fp[1];
          acc1[p][2] += wv[q] * fp[2];
        }
      }
    }
  }
  if (t < kHD) {
    #pragma unroll
    for (int p = 0; p < kP; ++p) {
      sk0L[p][t] = acc0[p];
      sk1L[p][t * 3 + 0] = acc1[p][0];
      sk1L[p][t * 3 + 1] = acc1[p][1];
      sk1L[p][t * 3 + 2] = acc1[p][2];
    }
  } else {
    const int o = t - kHD;
    #pragma unroll
    for (int p = 0; p < kP; ++p) {
      ws_sv0[(size_t)(i0 + p) * kHD + o] = acc0[p];
      float* sp = ws_sv1 + (size_t)(i0 + p) * kHD * 3 + o * 3;
      sp[0] = acc1[p][0]; sp[1] = acc1[p][1]; sp[2] = acc1[p][2];
    }
  }
  __syncthreads();

  if (t < kP * 16) {
    const int p = t >> 4, idx = t & 15;
    const int h = idx & 7;
    const bool is_self = idx >= 8;
    float s0 = 0.f, s1 = 0.f, bias;
    if (is_self) {
      #pragma unroll
      for (int d = 0; d < kD; ++d) s0 += q0s[p][h * kD + d] * sk0L[p][h * kD + d];
      #pragma unroll
      for (int x = 0; x < 48; ++x) s1 += q1s[p][h * 48 + x] * sk1L[p][h * 48 + x];
      bias = self_bias[h];
    } else {
      #pragma unroll
      for (int d = 0; d < kD; ++d) s0 += q0s[p][h * kD + d] * nk0[h * kD + d];
      #pragma unroll
      for (int x = 0; x < 48; ++x) s1 += q1s[p][h * 48 + x] * nk1[h * 48 + x];
      bias = null_bias[h];
    }
    float total = (s0 * SCALE0 + bias + s1 * SCALE1 * w1s[h]) * SHARED_S;
    ws_sc[(size_t)(i0 + p) * 272 + h * 34 + (is_self ? 1 : 0)] = total;
  }
}

// ---------------------------------------------------------------------------
// K2: neighbor similarities + fused softmax. P positions/block.
// ---------------------------------------------------------------------------
__global__ __launch_bounds__(256) void k2_sims(
    const float* __restrict__ q0, const float* __restrict__ q1,
    const float* __restrict__ k0, const float* __restrict__ k1,
    const float* __restrict__ edges, const float* __restrict__ Wbias,
    const float* __restrict__ hw1, const int* __restrict__ nmask,
    float* __restrict__ ws_sc)
{
  const int i0 = blockIdx.x * kP;
  const int t  = threadIdx.x;
  __shared__ float q0s[kP][kH * 17];
  __shared__ float q1s[kP][kH * 49];
  __shared__ float edg[kP][kN * 33];
  __shared__ float wbT[kE * kH];
  __shared__ float w1s[kH];
  __shared__ __align__(16) float scL[kP][272];

  for (int u = t; u < kP * 32; u += 256) { int p = u >> 5, r = u & 31;
    float4 v = ((const float4*)(q0 + (size_t)(i0 + p) * kHD))[r];
    int c = r * 4, h = c >> 4, d = c & 15;
    float* dst = &q0s[p][h * 17 + d];
    dst[0] = v.x; dst[1] = v.y; dst[2] = v.z; dst[3] = v.w; }
  for (int u = t; u < kP * 96; u += 256) { int p = u / 96, r = u % 96;
    float4 v = ((const float4*)(q1 + (size_t)(i0 + p) * kHD * 3))[r];
    int c = r * 4, h = c / 48, x = c % 48;
    float* dst = &q1s[p][h * 49 + x];
    dst[0] = v.x; dst[1] = v.y; dst[2] = v.z; dst[3] = v.w; }
  for (int u = t; u < kP * 256; u += 256) { int p = u >> 8, r = u & 255;
    float4 v = ((const float4*)(edges + (size_t)(i0 + p) * kN * kE))[r];
    int j = r >> 3, e4 = (r & 7) * 4;
    float* dst = &edg[p][j * 33 + e4];
    dst[0] = v.x; dst[1] = v.y; dst[2] = v.z; dst[3] = v.w; }
  if (t < kH * kE) { int h = t >> 5, e = t & 31; wbT[e * 8 + h] = Wbias[t]; }
  if (t < kH) w1s[t] = log1pf(expf(hw1[t]));
  if (t < kP * 16) { int p = t >> 4, idx = t & 15, h = idx & 7, slot = idx >> 3;
    scL[p][h * 34 + slot] = ws_sc[(size_t)(i0 + p) * 272 + h * 34 + slot]; }
  __syncthreads();

  {
    const int j = t >> 3, h = t & 7;
    #pragma unroll
    for (int p = 0; p < kP; ++p) {
      const int i = i0 + p;
      float bias = 0.f;
      #pragma unroll
      for (int e = 0; e < kE; ++e) bias += edg[p][j * 33 + e] * wbT[e * 8 + h];
      float s0 = 0.f;
      const float4* kr0 = (const float4*)(k0 + (size_t)(i * kN + j) * kHD + h * kD);
      #pragma unroll
      for (int g = 0; g < 4; ++g) {
        float4 w = kr0[g]; int x = h * 17 + g * 4;
        s0 += w.x * q0s[p][x] + w.y * q0s[p][x + 1]
            + w.z * q0s[p][x + 2] + w.w * q0s[p][x + 3];
      }
      float s1 = 0.f;
      const float4* kr1 = (const float4*)(k1 + (size_t)(i * kN + j) * kHD * 3 + h * 48);
      #pragma unroll
      for (int g = 0; g < 12; ++g) {
        float4 w = kr1[g]; int x = h * 49 + g * 4;
        s1 += w.x * q1s[p][x] + w.y * q1s[p][x + 1]
            + w.z * q1s[p][x + 2] + w.w * q1s[p][x + 3];
      }
      float total = (s0 * SCALE0 + bias + s1 * SCALE1 * w1s[h]) * SHARED_S;
      bool valid = nmask[(size_t)i * kN + j] != 0;
      scL[p][h * 34 + 2 + j] = valid ? total : NEGV;
    }
  }
  __syncthreads();

  if (t < kP * kH) {
    const int p = t >> 3, h = t & 7;
    float* row = &scL[p][h * 34];
    float mx = -1e30f;
    #pragma unroll
    for (int u = 0; u < 34; ++u) mx = fmaxf(mx, row[u]);
    float sum = 0.f;
    #pragma unroll
    for (int u = 0; u < 34; ++u) sum += __expf(row[u] - mx);
    float inv = 1.f / sum;
    #pragma unroll
    for (int u = 0; u < 34; ++u) row[u] = __expf(row[u] - mx) * inv;
  }
  __syncthreads();

  for (int u = t; u < kP * 68; u += 256) {
    int p = u / 68, r = u % 68;
    ((float4*)(ws_sc + (size_t)(i0 + p) * 272))[r] = ((float4*)scL[p])[r];
  }
}

// ---------------------------------------------------------------------------
// K3: attn-weighted V accumulation ONLY (projection split into k4_proj).
// One (position, float4-chunk) per thread; batched loads (8 in flight).
// Writes o0/o1 IN PLACE over ws_sv0/ws_sv1: each thread reads its sv chunk
// before writing its o chunk at the same address (same thread, race-free).
// __launch_bounds__(256,4): cap VGPR<=128 -> 16 waves/CU (was 200 VGPR / 8 waves).
// ---------------------------------------------------------------------------
__global__ __launch_bounds__(256, 4) void k3_accum(
    const float* __restrict__ v0, const float* __restrict__ v1,
    const float* __restrict__ nv0, const float* __restrict__ nv1,
    const float* __restrict__ ws_sc,
    float* __restrict__ ws_sv0, float* __restrict__ ws_sv1)
{
  const int i0 = blockIdx.x * kP3;
  const int t  = threadIdx.x;
  __shared__ __align__(16) float attnL[kP3][272];

  if (t < kP3 * 68) {
    int p = t / 68, r = t % 68;
    ((float4*)attnL[p])[r] = ((const float4*)(ws_sc + (size_t)(i0 + p) * 272))[r];
  }
  __syncthreads();

  // thread -> (p, s): p = t>>7, s = t&127. s<32: deg0 chunk s; else deg1 chunk s-32.
  const int p = t >> 7, i = i0 + p;
  const int s = t & 127;
  float4 acc;
  if (s < 32) {
    const int h = s >> 2;
    const float* at = attnL[p] + h * 34;
    float4 nv = ((const float4*)nv0)[s];
    float4 sv = ((const float4*)(ws_sv0 + (size_t)i * kHD))[s];
    acc.x = at[0] * nv.x + at[1] * sv.x;
    acc.y = at[0] * nv.y + at[1] * sv.y;
    acc.z = at[0] * nv.z + at[1] * sv.z;
    acc.w = at[0] * nv.w + at[1] * sv.w;
    const float4* vp = (const float4*)(v0 + (size_t)i * kN * kHD) + s;
    float4 vbuf[8];
    #pragma unroll
    for (int g = 0; g < 4; ++g) {
      #pragma unroll
      for (int r = 0; r < 8; ++r) vbuf[r] = vp[(g * 8 + r) * 32];
      #pragma unroll
      for (int r = 0; r < 8; ++r) {
        float a = at[2 + g * 8 + r];
        acc.x += a * vbuf[r].x; acc.y += a * vbuf[r].y;
        acc.z += a * vbuf[r].z; acc.w += a * vbuf[r].w;
      }
    }
    ((float4*)(ws_sv0 + (size_t)i * kHD))[s] = acc;   // o0 overlays sv0
  } else {
    const int s1 = s - 32;            // 0..95, never straddles a head (48%4==0)
    const int h = s1 / 12;
    const float* at = attnL[p] + h * 34;
    float4 nv = ((const float4*)nv1)[s1];
    float4 sv = ((const float4*)(ws_sv1 + (size_t)i * kHD * 3))[s1];
    acc.x = at[0] * nv.x + at[1] * sv.x;
    acc.y = at[0] * nv.y + at[1] * sv.y;
    acc.z = at[0] * nv.z + at[1] * sv.z;
    acc.w = at[0] * nv.w + at[1] * sv.w;
    const float4* vp = (const float4*)(v1 + (size_t)i * kN * kHD * 3) + s1;
    float4 vbuf[8];
    #pragma unroll
    for (int g = 0; g < 4; ++g) {
      #pragma unroll
      for (int r = 0; r < 8; ++r) vbuf[r] = vp[(g * 8 + r) * 96];
      #pragma unroll
      for (int r = 0; r < 8; ++r) {
        float a = at[2 + g * 8 + r];
        acc.x += a * vbuf[r].x; acc.y += a * vbuf[r].y;
        acc.z += a * vbuf[r].z; acc.w += a * vbuf[r].w;
      }
    }
    ((float4*)(ws_sv1 + (size_t)i * kHD * 3))[s1] = acc;  // o1 overlays sv1
  }
}

// ---------------------------------------------------------------------------
// K4: output projections. kPP=8 positions/block, 320 threads (one per output
// column: 128 deg0 + 192 deg1). W rows amortized over 8 positions (4x less
// W traffic than the old fused epilogue). o0/o1 staged in LDS (16.5 KB).
// ---------------------------------------------------------------------------
__global__ __launch_bounds__(320) void k4_proj(
    const float* __restrict__ ws_o0, const float* __restrict__ ws_o1,
    const float* __restrict__ Wout0, const float* __restrict__ Wout1,
    float* __restrict__ out, int n_total)
{
  const int i0 = blockIdx.x * kPP;
  const int t  = threadIdx.x;
  __shared__ __align__(16) float o0L[kPP][kHD];
  __shared__ __align__(16) float o1L[kPP][kHD * 3];

  for (int u = t; u < kPP * 32; u += 320) { int p = u >> 5, r = u & 31;
    ((float4*)o0L[p])[r] = ((const float4*)(ws_o0 + (size_t)(i0 + p) * kHD))[r]; }
  for (int u = t; u < kPP * 96; u += 320) { int p = u / 96, r = u % 96;
    ((float4*)o1L[p])[r] = ((const float4*)(ws_o1 + (size_t)(i0 + p) * kHD * 3))[r]; }
  __syncthreads();

  if (t < 128) {
    float acc[kPP] = {};
    const float4* wr = (const float4*)(Wout0 + t * kHD);
    #pragma unroll
    for (int g = 0; g < 32; ++g) {
      float4 w = wr[g]; int c = g * 4;
      #pragma unroll
      for (int p = 0; p < kPP; ++p)
        acc[p] += w.x * o0L[p][c] + w.y * o0L[p][c + 1]
                + w.z * o0L[p][c + 2] + w.w * o0L[p][c + 3];
    }
    #pragma unroll
    for (int p = 0; p < kPP; ++p) out[(size_t)(i0 + p) * kHD + t] = acc[p];
  } else {
    const int v2 = t - 128, o = v2 / 3, m = v2 - o * 3;
    float acc[kPP] = {};
    const float4* wr = (const float4*)(Wout1 + o * kHD);
    #pragma unroll
    for (int g = 0; g < 32; ++g) {
      float4 w = wr[g]; int c = g * 4;
      #pragma unroll
      for (int p = 0; p < kPP; ++p)
        acc[p] += w.x * o1L[p][(c + 0) * 3 + m] + w.y * o1L[p][(c + 1) * 3 + m]
                + w.z * o1L[p][(c + 2) * 3 + m] + w.w * o1L[p][(c + 3) * 3 + m];
    }
    #pragma unroll
    for (int p = 0; p < kPP; ++p)
      out[(size_t)n_total * kHD + (size_t)(i0 + p) * 192 + v2] = acc[p];
  }
}

extern "C" void kernel_launch(void* const* d_in, const int* in_sizes, int n_in,
                              void* d_out, int out_size, void* d_ws, size_t ws_size,
                              hipStream_t stream) {
  const int n = in_sizes[0] / kHD;  // 2048
  const float* q0     = (const float*)d_in[0];
  const float* k0     = (const float*)d_in[1];
  const float* v0     = (const float*)d_in[2];
  const float* q1     = (const float*)d_in[3];
  const float* k1     = (const float*)d_in[4];
  const float* v1     = (const float*)d_in[5];
  const float* feats0 = (const float*)d_in[6];
  const float* feats1 = (const float*)d_in[7];
  const float* edges  = (const float*)d_in[8];
  const float* Wskv0  = (const float*)d_in[9];
  const float* Wskv1  = (const float*)d_in[10];
  const float* Wbias  = (const float*)d_in[11];
  const float* sbias  = (const float*)d_in[12];
  const float* nbias  = (const float*)d_in[13];
  const float* nk0    = (const float*)d_in[14];
  const float* nv0    = (const float*)d_in[15];
  const float* nk1    = (const float*)d_in[16];
  const float* nv1    = (const float*)d_in[17];
  const float* hw1    = (const float*)d_in[18];
  const float* Wout0  = (const float*)d_in[19];
  const float* Wout1  = (const float*)d_in[20];
  const int*   nmask  = (const int*)d_in[21];

  float* ws     = (float*)d_ws;
  float* ws_sc  = ws;                                      // n*272
  float* ws_sv0 = ws + (size_t)n * 272;                    // n*128 (then o0)
  float* ws_sv1 = ws + (size_t)n * 272 + (size_t)n * 128;  // n*384 (then o1)

  k1_selfkv<<<n / kP, 256, 0, stream>>>(q0, q1, feats0, feats1, Wskv0, Wskv1,
                                        sbias, nbias, nk0, nk1, hw1,
                                        ws_sc, ws_sv0, ws_sv1);
  k2_sims<<<n / kP, 256, 0, stream>>>(q0, q1, k0, k1, edges, Wbias, hw1, nmask, ws_sc);
  k3_accum<<<n / kP3, 256, 0, stream>>>(v0, v1, nv0, nv1, ws_sc, ws_sv0, ws_sv1);
  k4_proj<<<n / kPP, 320, 0, stream>>>(ws_sv0, ws_sv1, Wout0, Wout1, (float*)d_out, n);
}